// Round 9
// baseline (230.971 us; speedup 1.0000x reference)
//
#include <hip/hip_runtime.h>

typedef __attribute__((ext_vector_type(8))) short bf16x8;
typedef __attribute__((ext_vector_type(4))) float f32x4;

__device__ __forceinline__ unsigned short f2bf(float f) {
  unsigned int u = __builtin_bit_cast(unsigned int, f);
  u += 0x7fffu + ((u >> 16) & 1u);   // RNE
  return (unsigned short)(u >> 16);
}

#define GLD16(gp, lp) __builtin_amdgcn_global_load_lds( \
    (const __attribute__((address_space(1))) unsigned int*)(gp), \
    (__attribute__((address_space(3))) unsigned int*)(lp), 16, 0, 0)

// ---------------------------------------------------------------------------
__global__ void detect_mode(const unsigned int* __restrict__ mask, int* __restrict__ flag) {
  __shared__ int c1s;
  if (threadIdx.x == 0) c1s = 0;
  __syncthreads();
  int c1 = 0;
  for (int i = threadIdx.x; i < 16384; i += 256) {
    unsigned int u = mask[i];
    if (u & 0x0000ff00u) c1++;
  }
  atomicAdd(&c1s, c1);
  __syncthreads();
  if (threadIdx.x == 0) *flag = (c1s > 0) ? 1 : 4;
}

// ---------------------------------------------------------------------------
__global__ __launch_bounds__(256) void pack_mask(
    const unsigned char* __restrict__ m, const int* __restrict__ flag,
    unsigned long long* __restrict__ pm)
{
  const int g = blockIdx.x * 256 + threadIdx.x;  // 0..524287
  const size_t base = (size_t)g * 64;
  unsigned long long bits = 0;
  if (*flag == 1) {
    const uint4* p = (const uint4*)(m + base);
#pragma unroll
    for (int j = 0; j < 4; ++j) {
      uint4 v = p[j];
      unsigned int w[4] = {v.x, v.y, v.z, v.w};
#pragma unroll
      for (int q = 0; q < 4; ++q) {
        unsigned int u = w[q];
#pragma unroll
        for (int b = 0; b < 4; ++b)
          if ((u >> (8 * b)) & 0xffu) bits |= 1ull << (j * 16 + q * 4 + b);
      }
    }
  } else {
    const uint4* p = (const uint4*)(m + base * 4);
#pragma unroll
    for (int j = 0; j < 16; ++j) {
      uint4 v = p[j];
      if (v.x) bits |= 1ull << (j * 4 + 0);
      if (v.y) bits |= 1ull << (j * 4 + 1);
      if (v.z) bits |= 1ull << (j * 4 + 2);
      if (v.w) bits |= 1ull << (j * 4 + 3);
    }
  }
  pm[g] = bits;
}

// ---------------------------------------------------------------------------
__global__ void cvt_two(const float* __restrict__ a, const float* __restrict__ b,
                        unsigned short* __restrict__ oa, unsigned short* __restrict__ ob) {
  int i = blockIdx.x * 256 + threadIdx.x;
  const float* src;
  unsigned short* dst;
  int j;
  if (i < 2097152) { src = a; dst = oa; j = i; }
  else             { src = b; dst = ob; j = i - 2097152; }
  float4 v = ((const float4*)src)[j];
  ushort4 o;
  o.x = f2bf(v.x); o.y = f2bf(v.y); o.z = f2bf(v.z); o.w = f2bf(v.w);
  ((ushort4*)dst)[j] = o;
}

__global__ void cvt_w3(const float* __restrict__ wq, const float* __restrict__ wk,
                       const float* __restrict__ wv,
                       unsigned short* __restrict__ oq, unsigned short* __restrict__ ok,
                       unsigned short* __restrict__ ov) {
  int idx = blockIdx.x * 256 + threadIdx.x;  // 0..786431
  int w = idx >> 18;
  int rem = idx & 262143;
  int n = rem >> 9, k = rem & 511;
  const float* W = (w == 0) ? wq : (w == 1) ? wk : wv;
  unsigned short* O = (w == 0) ? oq : (w == 1) ? ok : ov;
  O[n * 512 + k] = f2bf(W[k * 512 + n]);
}

// ---------------------------------------------------------------------------
// Unified 128x128 GEMM core. BK=32, 4 waves (wave 64x64), TRIPLE-buffered
// 16KB tiles (LDS 48KB -> 3 blocks/CU), counted vmcnt(8): 2 tiles in flight.
// Swizzle: 16B-chunk ^= (row ^ (row>>2)) & 3 -> uniform LDS bank spread on
// both stage (pre-swizzled global source, linear LDS dest) and ds_read.
// mode 0: bf16 C.  mode 1: scores epilogue (bitmask exp + rowsum atomics).
// mode 2: f32 C scaled by 1/sums[row].
__device__ __forceinline__ void core128(
    const unsigned short* __restrict__ Ab, const unsigned short* __restrict__ Bb,
    void* __restrict__ Cb, long ldA, long ldB, long ldO, int nk,
    long bm, long bn, char* smem, int mode,
    const unsigned long long* __restrict__ pmask, float* __restrict__ sumz,
    const float* __restrict__ sums_ro)
{
  const int tid = threadIdx.x;          // 0..255
  const int lane = tid & 63;
  const int wid = tid >> 6;             // 0..3
  const int wr = wid >> 1, wc = wid & 1;
  const int fr = lane & 15, fq = lane >> 4;

  char* b0 = smem;
  char* b1 = smem + 16384;
  char* b2 = smem + 32768;

  // staging: 2 slots/thread for A (8KB), 2 for B (8KB)
  const int s0 = tid, s1 = tid + 256;
  const int r0 = s0 >> 2, c0 = (s0 & 3) ^ ((r0 ^ (r0 >> 2)) & 3);
  const int r1 = s1 >> 2, c1 = (s1 & 3) ^ ((r1 ^ (r1 >> 2)) & 3);

#define STAGE(buf, kt) do { \
    const long k0_ = (long)(kt) << 5; \
    GLD16(Ab + (bm + r0) * ldA + k0_ + c0 * 8, (buf) + tid * 16); \
    GLD16(Ab + (bm + r1) * ldA + k0_ + c1 * 8, (buf) + 4096 + tid * 16); \
    GLD16(Bb + (bn + r0) * ldB + k0_ + c0 * 8, (buf) + 8192 + tid * 16); \
    GLD16(Bb + (bn + r1) * ldB + k0_ + c1 * 8, (buf) + 12288 + tid * 16); \
  } while (0)

  // ds_read byte offsets (per-thread constants)
  int aoff[4], boff[4];
#pragma unroll
  for (int i = 0; i < 4; ++i) {
    const int ra = wr * 64 + i * 16 + fr;
    aoff[i] = ra * 64 + (fq ^ ((ra ^ (ra >> 2)) & 3)) * 16;
    const int rb = wc * 64 + i * 16 + fr;
    boff[i] = 8192 + rb * 64 + (fq ^ ((rb ^ (rb >> 2)) & 3)) * 16;
  }

  f32x4 acc[4][4] = {};

  STAGE(b0, 0);
  STAGE(b1, 1);
  char* cur = b0; char* nx1 = b1; char* nx2 = b2;

  for (int t = 0; t < nk; ++t) {
    __builtin_amdgcn_sched_barrier(0);
    __builtin_amdgcn_s_barrier();       // all waves done reading nx2's old tile
    if (t + 2 < nk) {
      STAGE(nx2, t + 2);
      asm volatile("s_waitcnt vmcnt(8)" ::: "memory");   // tile t landed, 8 in flight
    } else if (t + 1 < nk) {
      asm volatile("s_waitcnt vmcnt(4)" ::: "memory");
    } else {
      asm volatile("s_waitcnt vmcnt(0)" ::: "memory");
    }
    __builtin_amdgcn_s_barrier();       // tile t visible to all waves
    __builtin_amdgcn_sched_barrier(0);

    bf16x8 a[4];
#pragma unroll
    for (int mi = 0; mi < 4; ++mi)
      a[mi] = *(const bf16x8*)(cur + aoff[mi]);
    __builtin_amdgcn_s_setprio(1);
#pragma unroll
    for (int nj = 0; nj < 4; ++nj) {
      const bf16x8 b = *(const bf16x8*)(cur + boff[nj]);
#pragma unroll
      for (int mi = 0; mi < 4; ++mi)
        acc[mi][nj] = __builtin_amdgcn_mfma_f32_16x16x32_bf16(a[mi], b, acc[mi][nj], 0, 0, 0);
    }
    __builtin_amdgcn_s_setprio(0);

    char* tmp = cur; cur = nx1; nx1 = nx2; nx2 = tmp;
  }
#undef STAGE

  // Epilogue. C/D layout: col=lane&15, row=(lane>>4)*4+r  [m89-verified]
  const float SCALE = 0.04419417382415922f;  // 1/sqrt(512)
  if (mode == 0) {
    unsigned short* C = (unsigned short*)Cb;
#pragma unroll
    for (int mi = 0; mi < 4; ++mi)
#pragma unroll
      for (int nj = 0; nj < 4; ++nj) {
        const long row = bm + wr * 64 + mi * 16 + fq * 4;
        const long col = bn + wc * 64 + nj * 16 + fr;
#pragma unroll
        for (int r = 0; r < 4; ++r)
          C[(row + r) * ldO + col] = f2bf(acc[mi][nj][r]);
      }
  } else if (mode == 1) {
    unsigned short* C = (unsigned short*)Cb;
    const long wword = (bn >> 6) + wc;
#pragma unroll
    for (int mi = 0; mi < 4; ++mi) {
      const long rowb = bm + wr * 64 + mi * 16 + fq * 4;
#pragma unroll
      for (int r = 0; r < 4; ++r) {
        const long row = rowb + r;
        const unsigned long long w = pmask[row * 32 + wword];
        unsigned short* Crow = C + row * ldO + bn + wc * 64 + fr;
        float s = 0.f;
#pragma unroll
        for (int nj = 0; nj < 4; ++nj) {
          const int sh = nj * 16 + fr;
          float e = ((w >> sh) & 1ull) ? 0.0f : __expf(acc[mi][nj][r] * SCALE);
          s += e;
          Crow[nj * 16] = f2bf(e);
        }
        s += __shfl_xor(s, 1); s += __shfl_xor(s, 2);
        s += __shfl_xor(s, 4); s += __shfl_xor(s, 8);
        if (fr == 0) atomicAdd(&sumz[row], s);
      }
    }
  } else {
    float* C = (float*)Cb;
#pragma unroll
    for (int mi = 0; mi < 4; ++mi) {
      const long rowb = bm + wr * 64 + mi * 16 + fq * 4;
#pragma unroll
      for (int r = 0; r < 4; ++r) {
        const long row = rowb + r;
        const float iv = 1.0f / sums_ro[row];
        const long colb = bn + wc * 64 + fr;
#pragma unroll
        for (int nj = 0; nj < 4; ++nj)
          C[row * ldO + colb + nj * 16] = acc[mi][nj][r] * iv;
      }
    }
  }
}

// Projections, grid(128,4,3):
//  z=0: Q = Xq*Wqt^T [16384x512]; z=1: K = Xn*Wkt^T; z=2: Vt = Wvt*Xn^T [512x16384]
__global__ __launch_bounds__(256, 3) void gemm_proj(
    const unsigned short* __restrict__ Xq, const unsigned short* __restrict__ Xn,
    const unsigned short* __restrict__ Wqt, const unsigned short* __restrict__ Wkt,
    const unsigned short* __restrict__ Wvt,
    unsigned short* __restrict__ Q, unsigned short* __restrict__ Kb,
    unsigned short* __restrict__ Vt)
{
  extern __shared__ char smem[];
  const int z = blockIdx.z;
  if (z == 0) {
    core128(Xq, Wqt, Q, 512, 512, 512, 16,
            (long)blockIdx.x * 128, (long)blockIdx.y * 128, smem, 0, nullptr, nullptr, nullptr);
  } else if (z == 1) {
    core128(Xn, Wkt, Kb, 512, 512, 512, 16,
            (long)blockIdx.x * 128, (long)blockIdx.y * 128, smem, 0, nullptr, nullptr, nullptr);
  } else {
    const int flat = blockIdx.x * 4 + blockIdx.y;        // 0..511
    core128(Wvt, Xn, Vt, 512, 512, 16384, 16,
            (long)(flat >> 7) * 128, (long)(flat & 127) * 128, smem, 0, nullptr, nullptr, nullptr);
  }
}

// Scores: E = exp(mask(QK^T)*scale) + row-sum atomics. grid(16,16,8).
__global__ __launch_bounds__(256, 3) void gemm_scores(
    const unsigned short* __restrict__ Q, const unsigned short* __restrict__ Kb,
    unsigned short* __restrict__ E, const unsigned long long* __restrict__ pm,
    float* __restrict__ sums)
{
  extern __shared__ char smem[];
  const long z = blockIdx.z;
  core128(Q + z * 1048576, Kb + z * 1048576, E + z * 4194304,
          512, 512, 2048, 16, (long)blockIdx.x * 128, (long)blockIdx.y * 128, smem,
          1, pm + z * 65536, sums + z * 2048, nullptr);
}

// PV: O = (E @ V) / rowsum, f32. grid(16,4,8), nk=64.
__global__ __launch_bounds__(256, 3) void gemm_pv(
    const unsigned short* __restrict__ E, const unsigned short* __restrict__ Vt,
    const float* __restrict__ sums, float* __restrict__ O)
{
  extern __shared__ char smem[];
  const long z = blockIdx.z;
  core128(E + z * 4194304, Vt + z * 2048, O + z * 1048576,
          2048, 16384, 512, 64, (long)blockIdx.x * 128, (long)blockIdx.y * 128, smem,
          2, nullptr, nullptr, sums + z * 2048);
}

// ---------------------------------------------------------------------------
extern "C" void kernel_launch(void* const* d_in, const int* in_sizes, int n_in,
                              void* d_out, int out_size, void* d_ws, size_t ws_size,
                              hipStream_t stream) {
  const float* node  = (const float*)d_in[0];
  const float* query = (const float*)d_in[1];
  const unsigned char* mask = (const unsigned char*)d_in[2];
  const float* wq = (const float*)d_in[3];
  const float* wk = (const float*)d_in[4];
  const float* wv = (const float*)d_in[5];
  float* out = (float*)d_out;

  char* ws = (char*)d_ws;
  // ws: Q[0,16M) K[16M,32M) Vt[32M,48M) E[48M,112M)
  //     (Xq/Xn/Wt overlap E, dead after proj)
  //     sums f32[8][2048] @112M, flag @112M+64K, packed mask @~113M
  unsigned short* Q   = (unsigned short*)(ws);
  unsigned short* Kb  = (unsigned short*)(ws + 16777216);
  unsigned short* Vt  = (unsigned short*)(ws + 33554432);
  unsigned short* E   = (unsigned short*)(ws + 50331648);
  unsigned short* Xq  = (unsigned short*)(ws + 50331648);
  unsigned short* Xn  = (unsigned short*)(ws + 50331648 + 16777216);
  unsigned short* Wqt = (unsigned short*)(ws + 50331648 + 33554432);
  unsigned short* Wkt = Wqt + 262144;
  unsigned short* Wvt = Wkt + 262144;
  float* sums = (float*)(ws + 117440512);
  int* flag   = (int*)(ws + 117506048);
  unsigned long long* pm = (unsigned long long*)(ws + 118489088);

  detect_mode<<<1, 256, 0, stream>>>((const unsigned int*)mask, flag);
  pack_mask<<<2048, 256, 0, stream>>>(mask, flag, pm);

  cvt_two<<<16384, 256, 0, stream>>>(query, node, Xq, Xn);
  cvt_w3<<<3072, 256, 0, stream>>>(wq, wk, wv, Wqt, Wkt, Wvt);

  // Projections: 1536 blocks at 3 blocks/CU -> 2 even rounds
  dim3 gp(128, 4, 3);
  gemm_proj<<<gp, 256, 49152, stream>>>(Xq, Xn, Wqt, Wkt, Wvt, Q, Kb, Vt);

  // Zero row-sum accumulators, then scores (+exp +mask +row sums)
  hipMemsetAsync(sums, 0, 65536, stream);
  dim3 gs(16, 16, 8);
  gemm_scores<<<gs, 256, 49152, stream>>>(Q, Kb, E, pm, sums);

  // PV + normalize
  dim3 gv(16, 4, 8);
  gemm_pv<<<gv, 256, 49152, stream>>>(E, Vt, sums, out);
}

// Round 10
// 228.891 us; speedup vs baseline: 1.0091x; 1.0091x over previous
//
#include <hip/hip_runtime.h>

typedef __attribute__((ext_vector_type(8))) short bf16x8;
typedef __attribute__((ext_vector_type(4))) float f32x4;

__device__ __forceinline__ unsigned short f2bf(float f) {
  unsigned int u = __builtin_bit_cast(unsigned int, f);
  u += 0x7fffu + ((u >> 16) & 1u);   // RNE
  return (unsigned short)(u >> 16);
}

#define GLD16(gp, lp) __builtin_amdgcn_global_load_lds( \
    (const __attribute__((address_space(1))) unsigned int*)(gp), \
    (__attribute__((address_space(3))) unsigned int*)(lp), 16, 0, 0)

// ---------------------------------------------------------------------------
__global__ void detect_mode(const unsigned int* __restrict__ mask, int* __restrict__ flag) {
  __shared__ int c1s;
  if (threadIdx.x == 0) c1s = 0;
  __syncthreads();
  int c1 = 0;
  for (int i = threadIdx.x; i < 16384; i += 256) {
    unsigned int u = mask[i];
    if (u & 0x0000ff00u) c1++;
  }
  atomicAdd(&c1s, c1);
  __syncthreads();
  if (threadIdx.x == 0) *flag = (c1s > 0) ? 1 : 4;
}

// ---------------------------------------------------------------------------
__global__ __launch_bounds__(256) void pack_mask(
    const unsigned char* __restrict__ m, const int* __restrict__ flag,
    unsigned long long* __restrict__ pm)
{
  const int g = blockIdx.x * 256 + threadIdx.x;  // 0..524287
  const size_t base = (size_t)g * 64;
  unsigned long long bits = 0;
  if (*flag == 1) {
    const uint4* p = (const uint4*)(m + base);
#pragma unroll
    for (int j = 0; j < 4; ++j) {
      uint4 v = p[j];
      unsigned int w[4] = {v.x, v.y, v.z, v.w};
#pragma unroll
      for (int q = 0; q < 4; ++q) {
        unsigned int u = w[q];
#pragma unroll
        for (int b = 0; b < 4; ++b)
          if ((u >> (8 * b)) & 0xffu) bits |= 1ull << (j * 16 + q * 4 + b);
      }
    }
  } else {
    const uint4* p = (const uint4*)(m + base * 4);
#pragma unroll
    for (int j = 0; j < 16; ++j) {
      uint4 v = p[j];
      if (v.x) bits |= 1ull << (j * 4 + 0);
      if (v.y) bits |= 1ull << (j * 4 + 1);
      if (v.z) bits |= 1ull << (j * 4 + 2);
      if (v.w) bits |= 1ull << (j * 4 + 3);
    }
  }
  pm[g] = bits;
}

// ---------------------------------------------------------------------------
__global__ void cvt_two(const float* __restrict__ a, const float* __restrict__ b,
                        unsigned short* __restrict__ oa, unsigned short* __restrict__ ob) {
  int i = blockIdx.x * 256 + threadIdx.x;
  const float* src;
  unsigned short* dst;
  int j;
  if (i < 2097152) { src = a; dst = oa; j = i; }
  else             { src = b; dst = ob; j = i - 2097152; }
  float4 v = ((const float4*)src)[j];
  ushort4 o;
  o.x = f2bf(v.x); o.y = f2bf(v.y); o.z = f2bf(v.z); o.w = f2bf(v.w);
  ((ushort4*)dst)[j] = o;
}

__global__ void cvt_w3(const float* __restrict__ wq, const float* __restrict__ wk,
                       const float* __restrict__ wv,
                       unsigned short* __restrict__ oq, unsigned short* __restrict__ ok,
                       unsigned short* __restrict__ ov) {
  int idx = blockIdx.x * 256 + threadIdx.x;  // 0..786431
  int w = idx >> 18;
  int rem = idx & 262143;
  int n = rem >> 9, k = rem & 511;
  const float* W = (w == 0) ? wq : (w == 1) ? wk : wv;
  unsigned short* O = (w == 0) ? oq : (w == 1) ? ok : ov;
  O[n * 512 + k] = f2bf(W[k * 512 + n]);
}

// ---------------------------------------------------------------------------
// Deep-pipelined GEMM skeleton: BK=32, 4 LDS buffers, stage tile t+3 during
// tile t (write buf (t+3)&3, read (t)&3 -> disjoint; B1 barrier proves buffer
// free). vmcnt ledger: steady 3 tiles in flight -> vmcnt(3L); tail 2L, L, 0.
// Swizzle: 16B-chunk ^= (row&3) on both pre-swizzled global source and
// ds_read -> uniform bank spread.
//
// Scores kernel: 256x256 tile, 8 waves (wave 64q x 128n), acc[4][8].
// E = masked ? 0 : exp(acc*SCALE); bf16 write + rowsum atomics.
__global__ __launch_bounds__(512, 1) void gemm_scores(
    const unsigned short* __restrict__ Qg, const unsigned short* __restrict__ Kg,
    unsigned short* __restrict__ Eg, const unsigned long long* __restrict__ pm,
    float* __restrict__ sums)
{
  extern __shared__ char smem[];
  // XCD swizzle: flat%8 = XCD = batch; panel = flat>>3
  const int flat = blockIdx.x + (blockIdx.y << 3) + (blockIdx.z << 6);  // 0..511
  const long z = flat & 7;
  const int p = flat >> 3;                      // 0..63
  const long bm = (long)(p & 7) * 256;
  const long bn = (long)(p >> 3) * 256;

  const unsigned short* Ab = Qg + z * 1048576;
  const unsigned short* Bb = Kg + z * 1048576;
  unsigned short* C = Eg + z * 4194304;
  const unsigned long long* pmask = pm + z * 65536;
  float* sumz = sums + z * 2048;

  const int tid = threadIdx.x;
  const int lane = tid & 63;
  const int wid = tid >> 6;
  const int wr = wid >> 1, wc = wid & 1;
  const int fr = lane & 15, fq = lane >> 4;

  // staging geometry: A 256x32 (16KB, 2 loads), B 256x32 (16KB, 2 loads)
  const int srow = tid >> 2;                    // 0..127
  const int sch = (tid & 3) ^ (srow & 3);       // pre-swizzled chunk

  char* bufs[4] = { smem, smem + 32768, smem + 65536, smem + 98304 };

#define STAGE_S(buf, kt) do { \
    const long k0_ = (long)(kt) << 5; \
    GLD16(Ab + (bm + srow) * 512 + k0_ + sch * 8,        (buf) + tid * 16); \
    GLD16(Ab + (bm + 128 + srow) * 512 + k0_ + sch * 8,  (buf) + 8192 + tid * 16); \
    GLD16(Bb + (bn + srow) * 512 + k0_ + sch * 8,        (buf) + 16384 + tid * 16); \
    GLD16(Bb + (bn + 128 + srow) * 512 + k0_ + sch * 8,  (buf) + 24576 + tid * 16); \
  } while (0)

  // ds_read byte offsets
  int aoff[4], boff[8];
#pragma unroll
  for (int i = 0; i < 4; ++i) {
    const int r = wr * 64 + i * 16 + fr;
    aoff[i] = r * 64 + (fq ^ (r & 3)) * 16;
  }
#pragma unroll
  for (int i = 0; i < 8; ++i) {
    const int r = wc * 128 + i * 16 + fr;
    boff[i] = 16384 + r * 64 + (fq ^ (r & 3)) * 16;
  }

  f32x4 acc[4][8] = {};

  STAGE_S(bufs[0], 0);
  STAGE_S(bufs[1], 1);
  STAGE_S(bufs[2], 2);
  char* c0 = bufs[0]; char* c1 = bufs[1]; char* c2 = bufs[2]; char* c3 = bufs[3];

  const int nk = 16;
  for (int t = 0; t < nk; ++t) {
    __builtin_amdgcn_sched_barrier(0);
    __builtin_amdgcn_s_barrier();               // B1: reads of c3's old tile done
    if (t + 3 < nk) {
      STAGE_S(c3, t + 3);
      asm volatile("s_waitcnt vmcnt(12)" ::: "memory");   // tile t landed
    } else if (t + 3 == nk) {
      asm volatile("s_waitcnt vmcnt(8)" ::: "memory");
    } else if (t + 2 == nk) {
      asm volatile("s_waitcnt vmcnt(4)" ::: "memory");
    } else {
      asm volatile("s_waitcnt vmcnt(0)" ::: "memory");
    }
    __builtin_amdgcn_s_barrier();               // B2: tile t visible
    __builtin_amdgcn_sched_barrier(0);

    bf16x8 a[4];
#pragma unroll
    for (int mi = 0; mi < 4; ++mi)
      a[mi] = *(const bf16x8*)(c0 + aoff[mi]);
    __builtin_amdgcn_s_setprio(1);
#pragma unroll
    for (int nj = 0; nj < 8; ++nj) {
      const bf16x8 b = *(const bf16x8*)(c0 + boff[nj]);
#pragma unroll
      for (int mi = 0; mi < 4; ++mi)
        acc[mi][nj] = __builtin_amdgcn_mfma_f32_16x16x32_bf16(a[mi], b, acc[mi][nj], 0, 0, 0);
    }
    __builtin_amdgcn_s_setprio(0);

    char* tmp = c0; c0 = c1; c1 = c2; c2 = c3; c3 = tmp;
  }
#undef STAGE_S

  // Epilogue (r7-verified): E = masked?0:exp(acc*SCALE), + rowsum atomics.
  const float SCALE = 0.04419417382415922f;  // 1/sqrt(512)
  const long wbase = (bn >> 6) + wc * 2;
#pragma unroll
  for (int mi = 0; mi < 4; ++mi) {
    const long rowb = bm + wr * 64 + mi * 16 + fq * 4;
#pragma unroll
    for (int r = 0; r < 4; ++r) {
      const long row = rowb + r;
      const unsigned long long w0 = pmask[row * 32 + wbase];
      const unsigned long long w1 = pmask[row * 32 + wbase + 1];
      unsigned short* Crow = C + row * 2048 + bn + wc * 128 + fr;
      float s = 0.f;
#pragma unroll
      for (int ni = 0; ni < 8; ++ni) {
        const unsigned long long w = (ni < 4) ? w0 : w1;
        const int sh = (ni & 3) * 16 + fr;
        float e = ((w >> sh) & 1ull) ? 0.0f : __expf(acc[mi][ni][r] * SCALE);
        s += e;
        Crow[ni * 16] = f2bf(e);
      }
      s += __shfl_xor(s, 1); s += __shfl_xor(s, 2);
      s += __shfl_xor(s, 4); s += __shfl_xor(s, 8);
      if (fr == 0) atomicAdd(&sumz[row], s);
    }
  }
}

// ---------------------------------------------------------------------------
// Narrow deep-pipelined core: BM=256, BN=128, BK=32, 8 waves (wave 64x64),
// 4 bufs x 24KB (A 16KB + B 8KB), 3 loads/tile, vmcnt ledger 9/6/3/0.
// mode 0: bf16 C.  mode 2: f32 C scaled by 1/sums[row].
__device__ __forceinline__ void narrow_core(
    const unsigned short* __restrict__ Ab, const unsigned short* __restrict__ Bb,
    void* __restrict__ Cb, long ldA, long ldB, long ldO, int nk,
    long bm, long bn, char* smem, int mode, const float* __restrict__ sums_ro)
{
  const int tid = threadIdx.x;
  const int lane = tid & 63;
  const int wid = tid >> 6;
  const int wr = wid >> 1, wc = wid & 1;
  const int fr = lane & 15, fq = lane >> 4;

  const int srow = tid >> 2;                    // 0..127
  const int sch = (tid & 3) ^ (srow & 3);

  char* bufs[4] = { smem, smem + 24576, smem + 49152, smem + 73728 };

#define STAGE_N(buf, kt) do { \
    const long k0_ = (long)(kt) << 5; \
    GLD16(Ab + (bm + srow) * ldA + k0_ + sch * 8,        (buf) + tid * 16); \
    GLD16(Ab + (bm + 128 + srow) * ldA + k0_ + sch * 8,  (buf) + 8192 + tid * 16); \
    GLD16(Bb + (bn + srow) * ldB + k0_ + sch * 8,        (buf) + 16384 + tid * 16); \
  } while (0)

  int aoff[4], boff[4];
#pragma unroll
  for (int i = 0; i < 4; ++i) {
    const int ra = wr * 64 + i * 16 + fr;
    aoff[i] = ra * 64 + (fq ^ (ra & 3)) * 16;
    const int rb = wc * 64 + i * 16 + fr;
    boff[i] = 16384 + rb * 64 + (fq ^ (rb & 3)) * 16;
  }

  f32x4 acc[4][4] = {};

  STAGE_N(bufs[0], 0);
  STAGE_N(bufs[1], 1);
  STAGE_N(bufs[2], 2);
  char* c0 = bufs[0]; char* c1 = bufs[1]; char* c2 = bufs[2]; char* c3 = bufs[3];

  for (int t = 0; t < nk; ++t) {
    __builtin_amdgcn_sched_barrier(0);
    __builtin_amdgcn_s_barrier();
    if (t + 3 < nk) {
      STAGE_N(c3, t + 3);
      asm volatile("s_waitcnt vmcnt(9)" ::: "memory");
    } else if (t + 3 == nk) {
      asm volatile("s_waitcnt vmcnt(6)" ::: "memory");
    } else if (t + 2 == nk) {
      asm volatile("s_waitcnt vmcnt(3)" ::: "memory");
    } else {
      asm volatile("s_waitcnt vmcnt(0)" ::: "memory");
    }
    __builtin_amdgcn_s_barrier();
    __builtin_amdgcn_sched_barrier(0);

    bf16x8 a[4];
#pragma unroll
    for (int mi = 0; mi < 4; ++mi)
      a[mi] = *(const bf16x8*)(c0 + aoff[mi]);
    __builtin_amdgcn_s_setprio(1);
#pragma unroll
    for (int nj = 0; nj < 4; ++nj) {
      const bf16x8 b = *(const bf16x8*)(c0 + boff[nj]);
#pragma unroll
      for (int mi = 0; mi < 4; ++mi)
        acc[mi][nj] = __builtin_amdgcn_mfma_f32_16x16x32_bf16(a[mi], b, acc[mi][nj], 0, 0, 0);
    }
    __builtin_amdgcn_s_setprio(0);

    char* tmp = c0; c0 = c1; c1 = c2; c2 = c3; c3 = tmp;
  }
#undef STAGE_N

  if (mode == 0) {
    unsigned short* C = (unsigned short*)Cb;
#pragma unroll
    for (int mi = 0; mi < 4; ++mi)
#pragma unroll
      for (int nj = 0; nj < 4; ++nj) {
        const long row = bm + wr * 64 + mi * 16 + fq * 4;
        const long col = bn + wc * 64 + nj * 16 + fr;
#pragma unroll
        for (int r = 0; r < 4; ++r)
          C[(row + r) * ldO + col] = f2bf(acc[mi][nj][r]);
      }
  } else {
    float* C = (float*)Cb;
#pragma unroll
    for (int mi = 0; mi < 4; ++mi) {
      const long rowb = bm + wr * 64 + mi * 16 + fq * 4;
#pragma unroll
      for (int r = 0; r < 4; ++r) {
        const long row = rowb + r;
        const float iv = 1.0f / sums_ro[row];
        const long colb = bn + wc * 64 + fr;
#pragma unroll
        for (int nj = 0; nj < 4; ++nj)
          C[row * ldO + colb + nj * 16] = acc[mi][nj][r] * iv;
      }
    }
  }
}

// Projections, grid(64,4,3):
//  z=0: Q = Xq*Wqt^T [16384x512]; z=1: K = Xn*Wkt^T; z=2: Vt = Wvt*Xn^T [512x16384]
__global__ __launch_bounds__(512, 1) void gemm_proj(
    const unsigned short* __restrict__ Xq, const unsigned short* __restrict__ Xn,
    const unsigned short* __restrict__ Wqt, const unsigned short* __restrict__ Wkt,
    const unsigned short* __restrict__ Wvt,
    unsigned short* __restrict__ Q, unsigned short* __restrict__ Kb,
    unsigned short* __restrict__ Vt)
{
  extern __shared__ char smem[];
  const int z = blockIdx.z;
  if (z == 0) {
    narrow_core(Xq, Wqt, Q, 512, 512, 512, 16,
                (long)blockIdx.x * 256, (long)blockIdx.y * 128, smem, 0, nullptr);
  } else if (z == 1) {
    narrow_core(Xn, Wkt, Kb, 512, 512, 512, 16,
                (long)blockIdx.x * 256, (long)blockIdx.y * 128, smem, 0, nullptr);
  } else {
    const int flat = blockIdx.x * 4 + blockIdx.y;     // 0..255
    narrow_core(Wvt, Xn, Vt, 512, 512, 16384, 16,
                (long)(flat >> 7) * 256, (long)(flat & 127) * 128, smem, 0, nullptr);
  }
}

// PV: O = (E @ V) / rowsum, f32. grid(8,4,8) flat-swizzled, nk=64.
__global__ __launch_bounds__(512, 1) void gemm_pv(
    const unsigned short* __restrict__ E, const unsigned short* __restrict__ Vt,
    const float* __restrict__ sums, float* __restrict__ O)
{
  extern __shared__ char smem[];
  const int flat = blockIdx.x + (blockIdx.y << 3) + (blockIdx.z << 5);  // 0..255
  const long z = flat & 7;
  const int p = flat >> 3;                      // 0..31
  narrow_core(E + z * 4194304, Vt + z * 2048, O + z * 1048576,
              2048, 16384, 512, 64,
              (long)(p & 7) * 256, (long)(p >> 3) * 128, smem,
              2, sums + z * 2048);
}

// ---------------------------------------------------------------------------
extern "C" void kernel_launch(void* const* d_in, const int* in_sizes, int n_in,
                              void* d_out, int out_size, void* d_ws, size_t ws_size,
                              hipStream_t stream) {
  const float* node  = (const float*)d_in[0];
  const float* query = (const float*)d_in[1];
  const unsigned char* mask = (const unsigned char*)d_in[2];
  const float* wq = (const float*)d_in[3];
  const float* wk = (const float*)d_in[4];
  const float* wv = (const float*)d_in[5];
  float* out = (float*)d_out;

  char* ws = (char*)d_ws;
  // ws: Q[0,16M) K[16M,32M) Vt[32M,48M) E[48M,112M)
  //     (Xq/Xn/Wt overlap E, dead after proj)
  //     sums f32[8][2048] @112M, flag @112M+64K, packed mask @~113M
  unsigned short* Q   = (unsigned short*)(ws);
  unsigned short* Kb  = (unsigned short*)(ws + 16777216);
  unsigned short* Vt  = (unsigned short*)(ws + 33554432);
  unsigned short* E   = (unsigned short*)(ws + 50331648);
  unsigned short* Xq  = (unsigned short*)(ws + 50331648);
  unsigned short* Xn  = (unsigned short*)(ws + 50331648 + 16777216);
  unsigned short* Wqt = (unsigned short*)(ws + 50331648 + 33554432);
  unsigned short* Wkt = Wqt + 262144;
  unsigned short* Wvt = Wkt + 262144;
  float* sums = (float*)(ws + 117440512);
  int* flag   = (int*)(ws + 117506048);
  unsigned long long* pm = (unsigned long long*)(ws + 118489088);

  detect_mode<<<1, 256, 0, stream>>>((const unsigned int*)mask, flag);
  pack_mask<<<2048, 256, 0, stream>>>(mask, flag, pm);

  cvt_two<<<16384, 256, 0, stream>>>(query, node, Xq, Xn);
  cvt_w3<<<3072, 256, 0, stream>>>(wq, wk, wv, Wqt, Wkt, Wvt);

  // Projections: 768 blocks = 3 even rounds at 1 block/CU
  dim3 gp(64, 4, 3);
  gemm_proj<<<gp, 512, 98304, stream>>>(Xq, Xn, Wqt, Wkt, Wvt, Q, Kb, Vt);

  // Zero row-sum accumulators, then scores (+exp +mask +row sums)
  hipMemsetAsync(sums, 0, 65536, stream);
  dim3 gs(8, 8, 8);
  gemm_scores<<<gs, 512, 131072, stream>>>(Q, Kb, E, pm, sums);

  // PV + normalize
  dim3 gv(8, 4, 8);
  gemm_pv<<<gv, 512, 98304, stream>>>(E, Vt, sums, out);
}

// Round 11
// 208.969 us; speedup vs baseline: 1.1053x; 1.0953x over previous
//
#include <hip/hip_runtime.h>

typedef __attribute__((ext_vector_type(8))) short bf16x8;
typedef __attribute__((ext_vector_type(4))) float f32x4;

__device__ __forceinline__ unsigned short f2bf(float f) {
  unsigned int u = __builtin_bit_cast(unsigned int, f);
  u += 0x7fffu + ((u >> 16) & 1u);   // RNE
  return (unsigned short)(u >> 16);
}

#define GLD16(gp, lp) __builtin_amdgcn_global_load_lds( \
    (const __attribute__((address_space(1))) unsigned int*)(gp), \
    (__attribute__((address_space(3))) unsigned int*)(lp), 16, 0, 0)

// ---------------------------------------------------------------------------
// Self-detecting mask pack: pm[g] bit b = (mask[g*64+b] != 0).
// Each block probes its own 16KB slice (1-byte view): any byte at pos%4==1
// nonzero <=> 1-byte bool elements (int32 0/1 masks have byte1 == 0 always;
// P(16K bools all-unmasked at byte1 positions) = 0.7^4096 ~ 0).
__global__ __launch_bounds__(256) void pack_mask(
    const unsigned char* __restrict__ m, unsigned long long* __restrict__ pm)
{
  __shared__ int mode1;
  if (threadIdx.x == 0) mode1 = 0;
  __syncthreads();

  const int g = blockIdx.x * 256 + threadIdx.x;  // 0..524287
  const size_t base = (size_t)g * 64;

  // 1-byte-view read of this thread's 64 bytes (valid memory in both modes)
  uint4 v[4];
  const uint4* p1 = (const uint4*)(m + base);
  v[0] = p1[0]; v[1] = p1[1]; v[2] = p1[2]; v[3] = p1[3];
  unsigned int probe = 0;
#pragma unroll
  for (int j = 0; j < 4; ++j)
    probe |= (v[j].x | v[j].y | v[j].z | v[j].w);
  if (probe & 0x0000ff00u) mode1 = 1;   // benign race
  __syncthreads();

  unsigned long long bits = 0;
  if (mode1) {
#pragma unroll
    for (int j = 0; j < 4; ++j) {
      unsigned int w[4] = {v[j].x, v[j].y, v[j].z, v[j].w};
#pragma unroll
      for (int q = 0; q < 4; ++q) {
        unsigned int u = w[q];
#pragma unroll
        for (int b = 0; b < 4; ++b)
          if ((u >> (8 * b)) & 0xffu) bits |= 1ull << (j * 16 + q * 4 + b);
      }
    }
  } else {
    const uint4* p4 = (const uint4*)(m + base * 4);
#pragma unroll
    for (int j = 0; j < 16; ++j) {
      uint4 w = p4[j];
      if (w.x) bits |= 1ull << (j * 4 + 0);
      if (w.y) bits |= 1ull << (j * 4 + 1);
      if (w.z) bits |= 1ull << (j * 4 + 2);
      if (w.w) bits |= 1ull << (j * 4 + 3);
    }
  }
  pm[g] = bits;
}

// ---------------------------------------------------------------------------
// One prep kernel: activation converts + weight transposes + sums zeroing.
// grid 19520 blocks x 256.
__global__ void prep(const float* __restrict__ query, const float* __restrict__ node,
                     const float* __restrict__ wq, const float* __restrict__ wk,
                     const float* __restrict__ wv,
                     unsigned short* __restrict__ Xq, unsigned short* __restrict__ Xn,
                     unsigned short* __restrict__ oq, unsigned short* __restrict__ ok,
                     unsigned short* __restrict__ ov, float* __restrict__ sums)
{
  const int b = blockIdx.x;
  if (b < 16384) {
    int i = b * 256 + threadIdx.x;           // float4 index
    const float* src;
    unsigned short* dst;
    int j;
    if (i < 2097152) { src = query; dst = Xq; j = i; }
    else             { src = node;  dst = Xn; j = i - 2097152; }
    float4 v = ((const float4*)src)[j];
    ushort4 o;
    o.x = f2bf(v.x); o.y = f2bf(v.y); o.z = f2bf(v.z); o.w = f2bf(v.w);
    ((ushort4*)dst)[j] = o;
  } else if (b < 19456) {
    int idx = (b - 16384) * 256 + threadIdx.x;  // 0..786431
    int w = idx >> 18;
    int rem = idx & 262143;
    int n = rem >> 9, k = rem & 511;
    const float* W = (w == 0) ? wq : (w == 1) ? wk : wv;
    unsigned short* O = (w == 0) ? oq : (w == 1) ? ok : ov;
    O[n * 512 + k] = f2bf(W[k * 512 + n]);
  } else {
    int idx = (b - 19456) * 256 + threadIdx.x;  // 0..16383
    sums[idx] = 0.0f;
  }
}

// ---------------------------------------------------------------------------
// Scores kernel (r10-verified): 256x256 tile, BK=32, 4 LDS buffers, stage
// t+3 during t, vmcnt ledger 12/8/4/0. XCD swizzle: batch = XCD, Q/K L2-fit.
// Epilogue: E = masked?0:exp(acc*SCALE) (packed bitmask) + rowsum atomics.
__global__ __launch_bounds__(512, 1) void gemm_scores(
    const unsigned short* __restrict__ Qg, const unsigned short* __restrict__ Kg,
    unsigned short* __restrict__ Eg, const unsigned long long* __restrict__ pm,
    float* __restrict__ sums)
{
  extern __shared__ char smem[];
  const int flat = blockIdx.x + (blockIdx.y << 3) + (blockIdx.z << 6);  // 0..511
  const long z = flat & 7;
  const int p = flat >> 3;                      // 0..63
  const long bm = (long)(p & 7) * 256;
  const long bn = (long)(p >> 3) * 256;

  const unsigned short* Ab = Qg + z * 1048576;
  const unsigned short* Bb = Kg + z * 1048576;
  unsigned short* C = Eg + z * 4194304;
  const unsigned long long* pmask = pm + z * 65536;
  float* sumz = sums + z * 2048;

  const int tid = threadIdx.x;
  const int lane = tid & 63;
  const int wid = tid >> 6;
  const int wr = wid >> 1, wc = wid & 1;
  const int fr = lane & 15, fq = lane >> 4;

  const int srow = tid >> 2;                    // 0..127
  const int sch = (tid & 3) ^ (srow & 3);       // pre-swizzled chunk

  char* bufs[4] = { smem, smem + 32768, smem + 65536, smem + 98304 };

#define STAGE_S(buf, kt) do { \
    const long k0_ = (long)(kt) << 5; \
    GLD16(Ab + (bm + srow) * 512 + k0_ + sch * 8,        (buf) + tid * 16); \
    GLD16(Ab + (bm + 128 + srow) * 512 + k0_ + sch * 8,  (buf) + 8192 + tid * 16); \
    GLD16(Bb + (bn + srow) * 512 + k0_ + sch * 8,        (buf) + 16384 + tid * 16); \
    GLD16(Bb + (bn + 128 + srow) * 512 + k0_ + sch * 8,  (buf) + 24576 + tid * 16); \
  } while (0)

  int aoff[4], boff[8];
#pragma unroll
  for (int i = 0; i < 4; ++i) {
    const int r = wr * 64 + i * 16 + fr;
    aoff[i] = r * 64 + (fq ^ (r & 3)) * 16;
  }
#pragma unroll
  for (int i = 0; i < 8; ++i) {
    const int r = wc * 128 + i * 16 + fr;
    boff[i] = 16384 + r * 64 + (fq ^ (r & 3)) * 16;
  }

  f32x4 acc[4][8] = {};

  STAGE_S(bufs[0], 0);
  STAGE_S(bufs[1], 1);
  STAGE_S(bufs[2], 2);
  char* c0 = bufs[0]; char* c1 = bufs[1]; char* c2 = bufs[2]; char* c3 = bufs[3];

  const int nk = 16;
  for (int t = 0; t < nk; ++t) {
    __builtin_amdgcn_sched_barrier(0);
    __builtin_amdgcn_s_barrier();               // B1: reads of c3's old tile done
    if (t + 3 < nk) {
      STAGE_S(c3, t + 3);
      asm volatile("s_waitcnt vmcnt(12)" ::: "memory");
    } else if (t + 3 == nk) {
      asm volatile("s_waitcnt vmcnt(8)" ::: "memory");
    } else if (t + 2 == nk) {
      asm volatile("s_waitcnt vmcnt(4)" ::: "memory");
    } else {
      asm volatile("s_waitcnt vmcnt(0)" ::: "memory");
    }
    __builtin_amdgcn_s_barrier();               // B2: tile t visible
    __builtin_amdgcn_sched_barrier(0);

    bf16x8 a[4];
#pragma unroll
    for (int mi = 0; mi < 4; ++mi)
      a[mi] = *(const bf16x8*)(c0 + aoff[mi]);
    __builtin_amdgcn_s_setprio(1);
#pragma unroll
    for (int nj = 0; nj < 8; ++nj) {
      const bf16x8 b = *(const bf16x8*)(c0 + boff[nj]);
#pragma unroll
      for (int mi = 0; mi < 4; ++mi)
        acc[mi][nj] = __builtin_amdgcn_mfma_f32_16x16x32_bf16(a[mi], b, acc[mi][nj], 0, 0, 0);
    }
    __builtin_amdgcn_s_setprio(0);

    char* tmp = c0; c0 = c1; c1 = c2; c2 = c3; c3 = tmp;
  }
#undef STAGE_S

  const float SCALE = 0.04419417382415922f;  // 1/sqrt(512)
  const long wbase = (bn >> 6) + wc * 2;
#pragma unroll
  for (int mi = 0; mi < 4; ++mi) {
    const long rowb = bm + wr * 64 + mi * 16 + fq * 4;
#pragma unroll
    for (int r = 0; r < 4; ++r) {
      const long row = rowb + r;
      const unsigned long long w0 = pmask[row * 32 + wbase];
      const unsigned long long w1 = pmask[row * 32 + wbase + 1];
      unsigned short* Crow = C + row * 2048 + bn + wc * 128 + fr;
      float s = 0.f;
#pragma unroll
      for (int ni = 0; ni < 8; ++ni) {
        const unsigned long long w = (ni < 4) ? w0 : w1;
        const int sh = (ni & 3) * 16 + fr;
        float e = ((w >> sh) & 1ull) ? 0.0f : __expf(acc[mi][ni][r] * SCALE);
        s += e;
        Crow[ni * 16] = f2bf(e);
      }
      s += __shfl_xor(s, 1); s += __shfl_xor(s, 2);
      s += __shfl_xor(s, 4); s += __shfl_xor(s, 8);
      if (fr == 0) atomicAdd(&sumz[row], s);
    }
  }
}

// ---------------------------------------------------------------------------
// Narrow deep-pipelined core (r10-verified): BM=256, BN=128, BK=32, 8 waves,
// 4 bufs x 24KB, vmcnt ledger 9/6/3/0.
// mode 0: bf16 C.  mode 2: f32 C scaled by 1/sums[row].
__device__ __forceinline__ void narrow_core(
    const unsigned short* __restrict__ Ab, const unsigned short* __restrict__ Bb,
    void* __restrict__ Cb, long ldA, long ldB, long ldO, int nk,
    long bm, long bn, char* smem, int mode, const float* __restrict__ sums_ro)
{
  const int tid = threadIdx.x;
  const int lane = tid & 63;
  const int wid = tid >> 6;
  const int wr = wid >> 1, wc = wid & 1;
  const int fr = lane & 15, fq = lane >> 4;

  const int srow = tid >> 2;                    // 0..127
  const int sch = (tid & 3) ^ (srow & 3);

  char* bufs[4] = { smem, smem + 24576, smem + 49152, smem + 73728 };

#define STAGE_N(buf, kt) do { \
    const long k0_ = (long)(kt) << 5; \
    GLD16(Ab + (bm + srow) * ldA + k0_ + sch * 8,        (buf) + tid * 16); \
    GLD16(Ab + (bm + 128 + srow) * ldA + k0_ + sch * 8,  (buf) + 8192 + tid * 16); \
    GLD16(Bb + (bn + srow) * ldB + k0_ + sch * 8,        (buf) + 16384 + tid * 16); \
  } while (0)

  int aoff[4], boff[4];
#pragma unroll
  for (int i = 0; i < 4; ++i) {
    const int ra = wr * 64 + i * 16 + fr;
    aoff[i] = ra * 64 + (fq ^ (ra & 3)) * 16;
    const int rb = wc * 64 + i * 16 + fr;
    boff[i] = 16384 + rb * 64 + (fq ^ (rb & 3)) * 16;
  }

  f32x4 acc[4][4] = {};

  STAGE_N(bufs[0], 0);
  STAGE_N(bufs[1], 1);
  STAGE_N(bufs[2], 2);
  char* c0 = bufs[0]; char* c1 = bufs[1]; char* c2 = bufs[2]; char* c3 = bufs[3];

  for (int t = 0; t < nk; ++t) {
    __builtin_amdgcn_sched_barrier(0);
    __builtin_amdgcn_s_barrier();
    if (t + 3 < nk) {
      STAGE_N(c3, t + 3);
      asm volatile("s_waitcnt vmcnt(9)" ::: "memory");
    } else if (t + 3 == nk) {
      asm volatile("s_waitcnt vmcnt(6)" ::: "memory");
    } else if (t + 2 == nk) {
      asm volatile("s_waitcnt vmcnt(3)" ::: "memory");
    } else {
      asm volatile("s_waitcnt vmcnt(0)" ::: "memory");
    }
    __builtin_amdgcn_s_barrier();
    __builtin_amdgcn_sched_barrier(0);

    bf16x8 a[4];
#pragma unroll
    for (int mi = 0; mi < 4; ++mi)
      a[mi] = *(const bf16x8*)(c0 + aoff[mi]);
    __builtin_amdgcn_s_setprio(1);
#pragma unroll
    for (int nj = 0; nj < 4; ++nj) {
      const bf16x8 b = *(const bf16x8*)(c0 + boff[nj]);
#pragma unroll
      for (int mi = 0; mi < 4; ++mi)
        acc[mi][nj] = __builtin_amdgcn_mfma_f32_16x16x32_bf16(a[mi], b, acc[mi][nj], 0, 0, 0);
    }
    __builtin_amdgcn_s_setprio(0);

    char* tmp = c0; c0 = c1; c1 = c2; c2 = c3; c3 = tmp;
  }
#undef STAGE_N

  if (mode == 0) {
    unsigned short* C = (unsigned short*)Cb;
#pragma unroll
    for (int mi = 0; mi < 4; ++mi)
#pragma unroll
      for (int nj = 0; nj < 4; ++nj) {
        const long row = bm + wr * 64 + mi * 16 + fq * 4;
        const long col = bn + wc * 64 + nj * 16 + fr;
#pragma unroll
        for (int r = 0; r < 4; ++r)
          C[(row + r) * ldO + col] = f2bf(acc[mi][nj][r]);
      }
  } else {
    float* C = (float*)Cb;
#pragma unroll
    for (int mi = 0; mi < 4; ++mi) {
      const long rowb = bm + wr * 64 + mi * 16 + fq * 4;
#pragma unroll
      for (int r = 0; r < 4; ++r) {
        const long row = rowb + r;
        const float iv = 1.0f / sums_ro[row];
        const long colb = bn + wc * 64 + fr;
#pragma unroll
        for (int nj = 0; nj < 4; ++nj)
          C[row * ldO + colb + nj * 16] = acc[mi][nj][r] * iv;
      }
    }
  }
}

// Projections, grid(64,4,3):
//  z=0: Q = Xq*Wqt^T [16384x512]; z=1: K = Xn*Wkt^T; z=2: Vt = Wvt*Xn^T [512x16384]
__global__ __launch_bounds__(512, 1) void gemm_proj(
    const unsigned short* __restrict__ Xq, const unsigned short* __restrict__ Xn,
    const unsigned short* __restrict__ Wqt, const unsigned short* __restrict__ Wkt,
    const unsigned short* __restrict__ Wvt,
    unsigned short* __restrict__ Q, unsigned short* __restrict__ Kb,
    unsigned short* __restrict__ Vt)
{
  extern __shared__ char smem[];
  const int z = blockIdx.z;
  if (z == 0) {
    narrow_core(Xq, Wqt, Q, 512, 512, 512, 16,
                (long)blockIdx.x * 256, (long)blockIdx.y * 128, smem, 0, nullptr);
  } else if (z == 1) {
    narrow_core(Xn, Wkt, Kb, 512, 512, 512, 16,
                (long)blockIdx.x * 256, (long)blockIdx.y * 128, smem, 0, nullptr);
  } else {
    const int flat = blockIdx.x * 4 + blockIdx.y;     // 0..255
    narrow_core(Wvt, Xn, Vt, 512, 512, 16384, 16,
                (long)(flat >> 7) * 256, (long)(flat & 127) * 128, smem, 0, nullptr);
  }
}

// PV: O = (E @ V) / rowsum, f32. grid(8,4,8), nk=64.
// L2-friendly order: within each XCD (batch), d-panel (bn) varies FASTEST so
// the 2MB Vt batch-slice stays L2-resident and each 2MB E-panel is read once.
__global__ __launch_bounds__(512, 1) void gemm_pv(
    const unsigned short* __restrict__ E, const unsigned short* __restrict__ Vt,
    const float* __restrict__ sums, float* __restrict__ O)
{
  extern __shared__ char smem[];
  const int flat = blockIdx.x + (blockIdx.y << 3) + (blockIdx.z << 5);  // 0..255
  const long z = flat & 7;                      // = XCD
  const int p = flat >> 3;                      // 0..31
  narrow_core(E + z * 4194304, Vt + z * 2048, O + z * 1048576,
              2048, 16384, 512, 64,
              (long)(p >> 2) * 256, (long)(p & 3) * 128, smem,
              2, sums + z * 2048);
}

// ---------------------------------------------------------------------------
extern "C" void kernel_launch(void* const* d_in, const int* in_sizes, int n_in,
                              void* d_out, int out_size, void* d_ws, size_t ws_size,
                              hipStream_t stream) {
  const float* node  = (const float*)d_in[0];
  const float* query = (const float*)d_in[1];
  const unsigned char* mask = (const unsigned char*)d_in[2];
  const float* wq = (const float*)d_in[3];
  const float* wk = (const float*)d_in[4];
  const float* wv = (const float*)d_in[5];
  float* out = (float*)d_out;

  char* ws = (char*)d_ws;
  // ws: Q[0,16M) K[16M,32M) Vt[32M,48M) E[48M,112M)
  //     (Xq/Xn/Wt overlap E, dead after proj)
  //     sums f32[8][2048] @112M, packed mask @~113M
  unsigned short* Q   = (unsigned short*)(ws);
  unsigned short* Kb  = (unsigned short*)(ws + 16777216);
  unsigned short* Vt  = (unsigned short*)(ws + 33554432);
  unsigned short* E   = (unsigned short*)(ws + 50331648);
  unsigned short* Xq  = (unsigned short*)(ws + 50331648);
  unsigned short* Xn  = (unsigned short*)(ws + 50331648 + 16777216);
  unsigned short* Wqt = (unsigned short*)(ws + 50331648 + 33554432);
  unsigned short* Wkt = Wqt + 262144;
  unsigned short* Wvt = Wkt + 262144;
  float* sums = (float*)(ws + 117440512);
  unsigned long long* pm = (unsigned long long*)(ws + 118489088);

  pack_mask<<<2048, 256, 0, stream>>>(mask, pm);
  prep<<<19520, 256, 0, stream>>>(query, node, wq, wk, wv,
                                  Xq, Xn, Wqt, Wkt, Wvt, sums);

  // Projections: 768 blocks = 3 even rounds at 1 block/CU
  dim3 gp(64, 4, 3);
  gemm_proj<<<gp, 512, 98304, stream>>>(Xq, Xn, Wqt, Wkt, Wvt, Q, Kb, Vt);

  // Scores (+exp +mask +row sums)
  dim3 gs(8, 8, 8);
  gemm_scores<<<gs, 512, 131072, stream>>>(Q, Kb, E, pm, sums);

  // PV + normalize
  dim3 gv(8, 4, 8);
  gemm_pv<<<gv, 512, 98304, stream>>>(E, Vt, sums, out);
}

// Round 12
// 198.924 us; speedup vs baseline: 1.1611x; 1.0505x over previous
//
#include <hip/hip_runtime.h>

typedef __attribute__((ext_vector_type(8))) short bf16x8;
typedef __attribute__((ext_vector_type(4))) float f32x4;

__device__ __forceinline__ unsigned short f2bf(float f) {
  unsigned int u = __builtin_bit_cast(unsigned int, f);
  u += 0x7fffu + ((u >> 16) & 1u);   // RNE
  return (unsigned short)(u >> 16);
}

#define GLD16(gp, lp) __builtin_amdgcn_global_load_lds( \
    (const __attribute__((address_space(1))) unsigned int*)(gp), \
    (__attribute__((address_space(3))) unsigned int*)(lp), 16, 0, 0)

// ---------------------------------------------------------------------------
// Self-detecting mask pack (r11-verified): pm[g] bit b = (mask[g*64+b] != 0).
__global__ __launch_bounds__(256) void pack_mask(
    const unsigned char* __restrict__ m, unsigned long long* __restrict__ pm)
{
  __shared__ int mode1;
  if (threadIdx.x == 0) mode1 = 0;
  __syncthreads();

  const int g = blockIdx.x * 256 + threadIdx.x;  // 0..524287
  const size_t base = (size_t)g * 64;

  uint4 v[4];
  const uint4* p1 = (const uint4*)(m + base);
  v[0] = p1[0]; v[1] = p1[1]; v[2] = p1[2]; v[3] = p1[3];
  unsigned int probe = 0;
#pragma unroll
  for (int j = 0; j < 4; ++j)
    probe |= (v[j].x | v[j].y | v[j].z | v[j].w);
  if (probe & 0x0000ff00u) mode1 = 1;   // benign race
  __syncthreads();

  unsigned long long bits = 0;
  if (mode1) {
#pragma unroll
    for (int j = 0; j < 4; ++j) {
      unsigned int w[4] = {v[j].x, v[j].y, v[j].z, v[j].w};
#pragma unroll
      for (int q = 0; q < 4; ++q) {
        unsigned int u = w[q];
#pragma unroll
        for (int b = 0; b < 4; ++b)
          if ((u >> (8 * b)) & 0xffu) bits |= 1ull << (j * 16 + q * 4 + b);
      }
    }
  } else {
    const uint4* p4 = (const uint4*)(m + base * 4);
#pragma unroll
    for (int j = 0; j < 16; ++j) {
      uint4 w = p4[j];
      if (w.x) bits |= 1ull << (j * 4 + 0);
      if (w.y) bits |= 1ull << (j * 4 + 1);
      if (w.z) bits |= 1ull << (j * 4 + 2);
      if (w.w) bits |= 1ull << (j * 4 + 3);
    }
  }
  pm[g] = bits;
}

// ---------------------------------------------------------------------------
// One prep kernel (r11-verified): converts + weight transposes + sums zeroing.
__global__ void prep(const float* __restrict__ query, const float* __restrict__ node,
                     const float* __restrict__ wq, const float* __restrict__ wk,
                     const float* __restrict__ wv,
                     unsigned short* __restrict__ Xq, unsigned short* __restrict__ Xn,
                     unsigned short* __restrict__ oq, unsigned short* __restrict__ ok,
                     unsigned short* __restrict__ ov, float* __restrict__ sums)
{
  const int b = blockIdx.x;
  if (b < 16384) {
    int i = b * 256 + threadIdx.x;
    const float* src;
    unsigned short* dst;
    int j;
    if (i < 2097152) { src = query; dst = Xq; j = i; }
    else             { src = node;  dst = Xn; j = i - 2097152; }
    float4 v = ((const float4*)src)[j];
    ushort4 o;
    o.x = f2bf(v.x); o.y = f2bf(v.y); o.z = f2bf(v.z); o.w = f2bf(v.w);
    ((ushort4*)dst)[j] = o;
  } else if (b < 19456) {
    int idx = (b - 16384) * 256 + threadIdx.x;
    int w = idx >> 18;
    int rem = idx & 262143;
    int n = rem >> 9, k = rem & 511;
    const float* W = (w == 0) ? wq : (w == 1) ? wk : wv;
    unsigned short* O = (w == 0) ? oq : (w == 1) ? ok : ov;
    O[n * 512 + k] = f2bf(W[k * 512 + n]);
  } else {
    int idx = (b - 19456) * 256 + threadIdx.x;
    sums[idx] = 0.0f;
  }
}

// ---------------------------------------------------------------------------
// Swizzle (fixed): 16B-chunk ^= ((row>>1)&3). With 64B rows, even rows all
// map to banks 0-15; (r>>1)&3 cycles all 4 chunks over the 8 even rows of a
// 16-lane group -> 2 lanes/chunk = free (m136). r&3 (old) gave 4-way.
//
// core128: 128x128 tile, BK=32, 4 waves (wave 64x64), 4 bufs x 16KB = 64KB
// -> 2 blocks/CU. Stage t+3 during t; vmcnt ledger 12/8/4/0 (L=4).
// mode 0: bf16 C.  mode 2: f32 C scaled by 1/sums[row].
__device__ __forceinline__ void core128(
    const unsigned short* __restrict__ Ab, const unsigned short* __restrict__ Bb,
    void* __restrict__ Cb, long ldA, long ldB, long ldO, int nk,
    long bm, long bn, char* smem, int mode, const float* __restrict__ sums_ro)
{
  const int tid = threadIdx.x;          // 0..255
  const int lane = tid & 63;
  const int wid = tid >> 6;
  const int wr = wid >> 1, wc = wid & 1;
  const int fr = lane & 15, fq = lane >> 4;

  const int srow = tid >> 2;            // 0..63
  const int sch = (tid & 3) ^ ((srow >> 1) & 3);   // pre-swizzled source chunk

  char* bufs[4] = { smem, smem + 16384, smem + 32768, smem + 49152 };

#define STAGE_C(buf, kt) do { \
    const long k0_ = (long)(kt) << 5; \
    GLD16(Ab + (bm + srow) * ldA + k0_ + sch * 8,        (buf) + tid * 16); \
    GLD16(Ab + (bm + 64 + srow) * ldA + k0_ + sch * 8,   (buf) + 4096 + tid * 16); \
    GLD16(Bb + (bn + srow) * ldB + k0_ + sch * 8,        (buf) + 8192 + tid * 16); \
    GLD16(Bb + (bn + 64 + srow) * ldB + k0_ + sch * 8,   (buf) + 12288 + tid * 16); \
  } while (0)

  int aoff[4], boff[4];
#pragma unroll
  for (int i = 0; i < 4; ++i) {
    const int ra = wr * 64 + i * 16 + fr;
    aoff[i] = ra * 64 + (fq ^ ((ra >> 1) & 3)) * 16;
    const int rb = wc * 64 + i * 16 + fr;
    boff[i] = 8192 + rb * 64 + (fq ^ ((rb >> 1) & 3)) * 16;
  }

  f32x4 acc[4][4] = {};

  STAGE_C(bufs[0], 0);
  STAGE_C(bufs[1], 1);
  STAGE_C(bufs[2], 2);
  char* c0 = bufs[0]; char* c1 = bufs[1]; char* c2 = bufs[2]; char* c3 = bufs[3];

  for (int t = 0; t < nk; ++t) {
    __builtin_amdgcn_sched_barrier(0);
    __builtin_amdgcn_s_barrier();       // B1: all reads of c3's old tile done
    if (t + 3 < nk) {
      STAGE_C(c3, t + 3);
      asm volatile("s_waitcnt vmcnt(12)" ::: "memory");   // tile t landed
    } else if (t + 3 == nk) {
      asm volatile("s_waitcnt vmcnt(8)" ::: "memory");
    } else if (t + 2 == nk) {
      asm volatile("s_waitcnt vmcnt(4)" ::: "memory");
    } else {
      asm volatile("s_waitcnt vmcnt(0)" ::: "memory");
    }
    __builtin_amdgcn_s_barrier();       // B2: tile t visible to all waves
    __builtin_amdgcn_sched_barrier(0);

    bf16x8 a[4];
#pragma unroll
    for (int mi = 0; mi < 4; ++mi)
      a[mi] = *(const bf16x8*)(c0 + aoff[mi]);
    __builtin_amdgcn_s_setprio(1);
#pragma unroll
    for (int nj = 0; nj < 4; ++nj) {
      const bf16x8 b = *(const bf16x8*)(c0 + boff[nj]);
#pragma unroll
      for (int mi = 0; mi < 4; ++mi)
        acc[mi][nj] = __builtin_amdgcn_mfma_f32_16x16x32_bf16(a[mi], b, acc[mi][nj], 0, 0, 0);
    }
    __builtin_amdgcn_s_setprio(0);

    char* tmp = c0; c0 = c1; c1 = c2; c2 = c3; c3 = tmp;
  }
#undef STAGE_C

  if (mode == 0) {
    unsigned short* C = (unsigned short*)Cb;
#pragma unroll
    for (int mi = 0; mi < 4; ++mi)
#pragma unroll
      for (int nj = 0; nj < 4; ++nj) {
        const long row = bm + wr * 64 + mi * 16 + fq * 4;
        const long col = bn + wc * 64 + nj * 16 + fr;
#pragma unroll
        for (int r = 0; r < 4; ++r)
          C[(row + r) * ldO + col] = f2bf(acc[mi][nj][r]);
      }
  } else {
    float* C = (float*)Cb;
#pragma unroll
    for (int mi = 0; mi < 4; ++mi) {
      const long rowb = bm + wr * 64 + mi * 16 + fq * 4;
#pragma unroll
      for (int r = 0; r < 4; ++r) {
        const long row = rowb + r;
        const float iv = 1.0f / sums_ro[row];
        const long colb = bn + wc * 64 + fr;
#pragma unroll
        for (int nj = 0; nj < 4; ++nj)
          C[row * ldO + colb + nj * 16] = acc[mi][nj][r] * iv;
      }
    }
  }
}

// ---------------------------------------------------------------------------
// Scores: 128x256 tile, BK=32, 4 waves (wave 64q x 128kv), 3 bufs x 24KB
// = 72KB -> 2 blocks/CU. Stage t+2 during t; vmcnt ledger 12/6/0 (L=6).
// Q/K L2-resident per XCD (batch = blockIdx.x = XCD).
// Epilogue: E = masked?0:exp(acc*SCALE) (packed bitmask) + rowsum atomics.
__global__ __launch_bounds__(256, 2) void gemm_scores(
    const unsigned short* __restrict__ Qg, const unsigned short* __restrict__ Kg,
    unsigned short* __restrict__ Eg, const unsigned long long* __restrict__ pm,
    float* __restrict__ sums)
{
  extern __shared__ char smem[];
  const long z = blockIdx.x;                    // batch = XCD
  const long bm = (long)blockIdx.y * 128;       // q panel
  const long bn = (long)blockIdx.z * 256;       // kv panel

  const unsigned short* Ab = Qg + z * 1048576;
  const unsigned short* Bb = Kg + z * 1048576;
  unsigned short* C = Eg + z * 4194304;
  const unsigned long long* pmask = pm + z * 65536;
  float* sumz = sums + z * 2048;

  const int tid = threadIdx.x;
  const int lane = tid & 63;
  const int wid = tid >> 6;
  const int wr = wid >> 1, wc = wid & 1;
  const int fr = lane & 15, fq = lane >> 4;

  const int srow = tid >> 2;                    // 0..63
  const int sch = (tid & 3) ^ ((srow >> 1) & 3);

  char* bufs[3] = { smem, smem + 24576, smem + 49152 };

#define STAGE_S(buf, kt) do { \
    const long k0_ = (long)(kt) << 5; \
    GLD16(Ab + (bm + srow) * 512 + k0_ + sch * 8,        (buf) + tid * 16); \
    GLD16(Ab + (bm + 64 + srow) * 512 + k0_ + sch * 8,   (buf) + 4096 + tid * 16); \
    GLD16(Bb + (bn + srow) * 512 + k0_ + sch * 8,        (buf) + 8192 + tid * 16); \
    GLD16(Bb + (bn + 64 + srow) * 512 + k0_ + sch * 8,   (buf) + 12288 + tid * 16); \
    GLD16(Bb + (bn + 128 + srow) * 512 + k0_ + sch * 8,  (buf) + 16384 + tid * 16); \
    GLD16(Bb + (bn + 192 + srow) * 512 + k0_ + sch * 8,  (buf) + 20480 + tid * 16); \
  } while (0)

  int aoff[4], boff[8];
#pragma unroll
  for (int i = 0; i < 4; ++i) {
    const int r = wr * 64 + i * 16 + fr;
    aoff[i] = r * 64 + (fq ^ ((r >> 1) & 3)) * 16;
  }
#pragma unroll
  for (int i = 0; i < 8; ++i) {
    const int r = wc * 128 + i * 16 + fr;
    boff[i] = 8192 + r * 64 + (fq ^ ((r >> 1) & 3)) * 16;
  }

  f32x4 acc[4][8] = {};

  STAGE_S(bufs[0], 0);
  STAGE_S(bufs[1], 1);
  char* c0 = bufs[0]; char* c1 = bufs[1]; char* c2 = bufs[2];

  const int nk = 16;
  for (int t = 0; t < nk; ++t) {
    __builtin_amdgcn_sched_barrier(0);
    __builtin_amdgcn_s_barrier();               // B1: reads of c2's old tile done
    if (t + 2 < nk) {
      STAGE_S(c2, t + 2);
      asm volatile("s_waitcnt vmcnt(12)" ::: "memory");   // tile t landed
    } else if (t + 2 == nk) {
      asm volatile("s_waitcnt vmcnt(6)" ::: "memory");
    } else {
      asm volatile("s_waitcnt vmcnt(0)" ::: "memory");
    }
    __builtin_amdgcn_s_barrier();               // B2: tile t visible
    __builtin_amdgcn_sched_barrier(0);

    bf16x8 a[4];
#pragma unroll
    for (int mi = 0; mi < 4; ++mi)
      a[mi] = *(const bf16x8*)(c0 + aoff[mi]);
    __builtin_amdgcn_s_setprio(1);
#pragma unroll
    for (int nj = 0; nj < 8; ++nj) {
      const bf16x8 b = *(const bf16x8*)(c0 + boff[nj]);
#pragma unroll
      for (int mi = 0; mi < 4; ++mi)
        acc[mi][nj] = __builtin_amdgcn_mfma_f32_16x16x32_bf16(a[mi], b, acc[mi][nj], 0, 0, 0);
    }
    __builtin_amdgcn_s_setprio(0);

    char* tmp = c0; c0 = c1; c1 = c2; c2 = tmp;
  }
#undef STAGE_S

  const float SCALE = 0.04419417382415922f;  // 1/sqrt(512)
  const long wbase = (bn >> 6) + wc * 2;
#pragma unroll
  for (int mi = 0; mi < 4; ++mi) {
    const long rowb = bm + wr * 64 + mi * 16 + fq * 4;
#pragma unroll
    for (int r = 0; r < 4; ++r) {
      const long row = rowb + r;
      const unsigned long long w0 = pmask[row * 32 + wbase];
      const unsigned long long w1 = pmask[row * 32 + wbase + 1];
      unsigned short* Crow = C + row * 2048 + bn + wc * 128 + fr;
      float s = 0.f;
#pragma unroll
      for (int ni = 0; ni < 8; ++ni) {
        const unsigned long long w = (ni < 4) ? w0 : w1;
        const int sh = (ni & 3) * 16 + fr;
        float e = ((w >> sh) & 1ull) ? 0.0f : __expf(acc[mi][ni][r] * SCALE);
        s += e;
        Crow[ni * 16] = f2bf(e);
      }
      s += __shfl_xor(s, 1); s += __shfl_xor(s, 2);
      s += __shfl_xor(s, 4); s += __shfl_xor(s, 8);
      if (fr == 0) atomicAdd(&sumz[row], s);
    }
  }
}

// Projections, grid(128,4,3), 256 threads:
//  z=0: Q = Xq*Wqt^T; z=1: K = Xn*Wkt^T; z=2: Vt = Wvt*Xn^T [512x16384]
__global__ __launch_bounds__(256, 2) void gemm_proj(
    const unsigned short* __restrict__ Xq, const unsigned short* __restrict__ Xn,
    const unsigned short* __restrict__ Wqt, const unsigned short* __restrict__ Wkt,
    const unsigned short* __restrict__ Wvt,
    unsigned short* __restrict__ Q, unsigned short* __restrict__ Kb,
    unsigned short* __restrict__ Vt)
{
  extern __shared__ char smem[];
  const int z = blockIdx.z;
  if (z == 0) {
    core128(Xq, Wqt, Q, 512, 512, 512, 16,
            (long)blockIdx.x * 128, (long)blockIdx.y * 128, smem, 0, nullptr);
  } else if (z == 1) {
    core128(Xn, Wkt, Kb, 512, 512, 512, 16,
            (long)blockIdx.x * 128, (long)blockIdx.y * 128, smem, 0, nullptr);
  } else {
    core128(Wvt, Xn, Vt, 512, 512, 16384, 16,
            (long)blockIdx.y * 128, (long)blockIdx.x * 128, smem, 0, nullptr);
  }
}

// PV: O = (E @ V) / rowsum, f32. grid(8,16,4): batch = XCD, Vt L2-resident.
__global__ __launch_bounds__(256, 2) void gemm_pv(
    const unsigned short* __restrict__ E, const unsigned short* __restrict__ Vt,
    const float* __restrict__ sums, float* __restrict__ O)
{
  extern __shared__ char smem[];
  const long z = blockIdx.x;                    // batch = XCD
  core128(E + z * 4194304, Vt + z * 2048, O + z * 1048576,
          2048, 16384, 512, 64,
          (long)blockIdx.y * 128, (long)blockIdx.z * 128, smem,
          2, sums + z * 2048);
}

// ---------------------------------------------------------------------------
extern "C" void kernel_launch(void* const* d_in, const int* in_sizes, int n_in,
                              void* d_out, int out_size, void* d_ws, size_t ws_size,
                              hipStream_t stream) {
  const float* node  = (const float*)d_in[0];
  const float* query = (const float*)d_in[1];
  const unsigned char* mask = (const unsigned char*)d_in[2];
  const float* wq = (const float*)d_in[3];
  const float* wk = (const float*)d_in[4];
  const float* wv = (const float*)d_in[5];
  float* out = (float*)d_out;

  char* ws = (char*)d_ws;
  // ws: Q[0,16M) K[16M,32M) Vt[32M,48M) E[48M,112M)
  //     (Xq/Xn/Wt overlap E, dead after proj)
  //     sums f32[8][2048] @112M, packed mask @~113M
  unsigned short* Q   = (unsigned short*)(ws);
  unsigned short* Kb  = (unsigned short*)(ws + 16777216);
  unsigned short* Vt  = (unsigned short*)(ws + 33554432);
  unsigned short* E   = (unsigned short*)(ws + 50331648);
  unsigned short* Xq  = (unsigned short*)(ws + 50331648);
  unsigned short* Xn  = (unsigned short*)(ws + 50331648 + 16777216);
  unsigned short* Wqt = (unsigned short*)(ws + 50331648 + 33554432);
  unsigned short* Wkt = Wqt + 262144;
  unsigned short* Wvt = Wkt + 262144;
  float* sums = (float*)(ws + 117440512);
  unsigned long long* pm = (unsigned long long*)(ws + 118489088);

  pack_mask<<<2048, 256, 0, stream>>>(mask, pm);
  prep<<<19520, 256, 0, stream>>>(query, node, wq, wk, wv,
                                  Xq, Xn, Wqt, Wkt, Wvt, sums);

  // Projections: 1536 blocks at 2 blocks/CU -> 3 even rounds
  dim3 gp(128, 4, 3);
  gemm_proj<<<gp, 256, 65536, stream>>>(Xq, Xn, Wqt, Wkt, Wvt, Q, Kb, Vt);

  // Scores (+exp +mask +row sums): 1024 blocks -> 2 even rounds
  dim3 gs(8, 16, 8);
  gemm_scores<<<gs, 256, 73728, stream>>>(Q, Kb, E, pm, sums);

  // PV + normalize: 512 blocks -> 1 even round
  dim3 gv(8, 16, 4);
  gemm_pv<<<gv, 256, 65536, stream>>>(E, Vt, sums, out);
}